// Round 2
// baseline (295.185 us; speedup 1.0000x reference)
//
#include <hip/hip_runtime.h>

#define DEV __device__ __forceinline__

constexpr int H  = 128;
constexpr int BP = 32;        // B*P
constexpr int NR = 2048;      // BP*64 rows

// workspace layout (float offsets)
constexpr int WH_OFF    = 0;                       // [2048][128] weapon_h
constexpr int TH_OFF    = WH_OFF + NR*H;           // [2048][128] target_h
constexpr int WHS_OFF   = TH_OFF + NR*H;           // [32][128] weapon_h.sum(axis=2)
constexpr int THS_OFF   = WHS_OFF + BP*H;          // [32][128]
constexpr int V1_OFF    = THS_OFF + BP*H;          // [128]
constexpr int C0_OFF    = V1_OFF + H;              // [128]
constexpr int WT1_OFF   = C0_OFF + H;              // [128][640]  eaT|waT|whh_wT
constexpr int WT2_OFF   = WT1_OFF + 128*640;       // [128][640]  ebT|taT|whh_tT
constexpr int WCT_OFF   = WT2_OFF + 128*640;       // [128][128]
constexpr int TCT_OFF   = WCT_OFF + 128*128;
constexpr int WIHWT_OFF = TCT_OFF + 128*128;       // [128][384]
constexpr int WIHTT_OFF = WIHWT_OFF + 128*384;
constexpr int WBT_OFF   = WIHTT_OFF + 128*384;     // [128][128]
constexpr int TBT_OFF   = WBT_OFF + 128*128;
constexpr int OUT1_OFF  = TBT_OFF + 128*128;       // [2048][640]  A|WA|ghw
constexpr int OUT2_OFF  = OUT1_OFF + NR*640;       // [2048][640]  Bt|TA|ght
constexpr int ESW_OFF   = OUT2_OFF + NR*640;       // [2048][128] edge sum over t
constexpr int ESTP_OFF  = ESW_OFF + NR*H;          // [16][2048][128] partial sums over w
constexpr int WBV_OFF   = ESTP_OFF + 16*NR*H;      // [32][128]
constexpr int TBV_OFF   = WBV_OFF + BP*H;          // [32][128]

DEV float fast_tanh(float x) {
  float e = __builtin_amdgcn_exp2f(x * 2.8853900817779268f);  // exp(2x)
  return fmaf(-2.0f, __builtin_amdgcn_rcpf(e + 1.0f), 1.0f);
}
DEV float fast_sigmoid(float x) {
  float e = __builtin_amdgcn_exp2f(x * -1.4426950408889634f); // exp(-x)
  return __builtin_amdgcn_rcpf(1.0f + e);
}

// ---------------- K1: projections + weight transposes + sums + v1/c0 ----------------
__global__ __launch_bounds__(256) void k1_proj_transpose(
    const float* __restrict__ wf, const float* __restrict__ tf,
    const float* __restrict__ wp_w, const float* __restrict__ wp_b,
    const float* __restrict__ tp_w, const float* __restrict__ tp_b,
    const float* __restrict__ eu_w, const float* __restrict__ wm_w,
    const float* __restrict__ tm_w,
    const float* __restrict__ whh_w, const float* __restrict__ whh_t,
    const float* __restrict__ wih_w, const float* __restrict__ wih_t,
    const float* __restrict__ ep_w, const float* __restrict__ ep_b,
    const float* __restrict__ eu_b,
    float* __restrict__ ws)
{
  __shared__ float fs[2][32][4];
  int bid = blockIdx.x, tid = threadIdx.x;
  if (bid < 2048) {
    int gid = bid*256 + tid;
    int m = gid >> 7;       // 0..4095
    int j = gid & 127;
    int side = m >> 11;
    int n = m & 2047;
    const float* F  = side ? tf : wf;
    const float* Pw = side ? tp_w : wp_w;
    const float* Pb = side ? tp_b : wp_b;
    float4 x  = *(const float4*)&F[n*4];
    float4 wv = *(const float4*)&Pw[j*4];
    float v = x.x*wv.x + x.y*wv.y + x.z*wv.z + x.w*wv.w + Pb[j];
    ws[(side ? TH_OFF : WH_OFF) + n*H + j] = v;
  } else if (bid < 3328) {
    int idx = (bid - 2048)*256 + tid;
    if (idx < 131072) {                  // 8 transposes of 128x128 slices
      int which = idx >> 14;
      int r = idx & 16383;
      int k = r >> 7, j = r & 127;
      float v; float* dst;
      switch (which) {
        case 0: v = eu_w[j*384 + k];        dst = ws + WT1_OFF + k*640 + j;       break;
        case 1: v = wm_w[j*384 + k];        dst = ws + WT1_OFF + k*640 + 128 + j; break;
        case 2: v = eu_w[j*384 + 128 + k];  dst = ws + WT2_OFF + k*640 + j;       break;
        case 3: v = tm_w[j*384 + k];        dst = ws + WT2_OFF + k*640 + 128 + j; break;
        case 4: v = wm_w[j*384 + 256 + k];  dst = ws + WCT_OFF + k*128 + j;       break;
        case 5: v = tm_w[j*384 + 256 + k];  dst = ws + TCT_OFF + k*128 + j;       break;
        case 6: v = wm_w[j*384 + 128 + k];  dst = ws + WBT_OFF + k*128 + j;       break;
        default:v = tm_w[j*384 + 128 + k];  dst = ws + TBT_OFF + k*128 + j;       break;
      }
      *dst = v;
    } else {                             // 4 transposes of 384x128 GRU weights
      int idx2 = idx - 131072;
      int which = idx2 / 49152;
      int r = idx2 % 49152;
      int k = r / 384, j = r % 384;
      float v; float* dst;
      switch (which) {
        case 0: v = whh_w[j*128 + k]; dst = ws + WT1_OFF + k*640 + 256 + j; break;
        case 1: v = whh_t[j*128 + k]; dst = ws + WT2_OFF + k*640 + 256 + j; break;
        case 2: v = wih_w[j*128 + k]; dst = ws + WIHWT_OFF + k*384 + j;     break;
        default:v = wih_t[j*128 + k]; dst = ws + WIHTT_OFF + k*384 + j;     break;
      }
      *dst = v;
    }
  } else {
    // sums block: feature sums -> WHS/THS, plus v1/c0
    {
      int side = tid >> 7, r = tid & 127;
      int bp = r >> 2, c = r & 3;
      const float* F = side ? tf : wf;
      float s = 0.f;
      #pragma unroll 8
      for (int w = 0; w < 64; ++w) s += F[bp*256 + w*4 + c];
      fs[side][bp][c] = s;
    }
    __syncthreads();
    {
      int side = tid >> 7, j = tid & 127;
      const float* Pw = side ? tp_w : wp_w;
      const float* Pb = side ? tp_b : wp_b;
      float4 wv = *(const float4*)&Pw[j*4];
      float pb = Pb[j] * 64.f;
      float* dst = ws + (side ? THS_OFF : WHS_OFF) + j;
      #pragma unroll 4
      for (int bp = 0; bp < 32; ++bp) {
        float4 f = *(const float4*)&fs[side][bp][0];
        dst[bp*128] = f.x*wv.x + f.y*wv.y + f.z*wv.z + f.w*wv.w + pb;
      }
    }
    if (tid < 128) {
      int j = tid;
      float s1 = 0.f, s0 = 0.f;
      for (int k = 0; k < 128; ++k) {
        float ec = eu_w[j*384 + 256 + k];
        s1 = fmaf(ec, ep_w[k], s1);
        s0 = fmaf(ec, ep_b[k], s0);
      }
      ws[V1_OFF + j] = s1;
      ws[C0_OFF + j] = s0 + eu_b[j];
    }
  }
}

// ---------------- generic tile fp32 GEMM core (K=128, 128-wide col tile) ----------------
#define FMA4(A, s, Wv) do { A.x = fmaf(s, Wv.x, A.x); A.y = fmaf(s, Wv.y, A.y); \
                            A.z = fmaf(s, Wv.z, A.z); A.w = fmaf(s, Wv.w, A.w); } while (0)

DEV void stage_x_direct(float* Xs, const float* __restrict__ X, int row0, int tid) {
  const float* src = X + row0*128;
  #pragma unroll
  for (int q = 0; q < 4; ++q) {
    int idx = q*1024 + tid*4;
    *(float4*)&Xs[idx] = *(const float4*)&src[idx];
  }
}

template<int RPT, int NTHR>
DEV void gemm_core2(const float* __restrict__ Wt, int ldw, int j0,
                    const float* Xs, float* Ws, int tid, float4* acc)
{
  const int tc = tid & 31, tr = tid >> 5;
  const int jj = tc*4, r0 = tr*RPT;
  #pragma unroll
  for (int i = 0; i < RPT; ++i) acc[i] = make_float4(0.f, 0.f, 0.f, 0.f);
  for (int kc = 0; kc < 128; kc += 32) {
    __syncthreads();
    #pragma unroll
    for (int q = 0; q < 4096/(NTHR*4); ++q) {
      int idx = q*(NTHR*4) + tid*4;
      int kk = idx >> 7, jx = idx & 127;
      *(float4*)&Ws[idx] = *(const float4*)&Wt[(kc+kk)*ldw + j0 + jx];
    }
    __syncthreads();
    #pragma unroll
    for (int kk = 0; kk < 32; kk += 4) {
      float4 w0 = *(const float4*)&Ws[(kk+0)*128 + jj];
      float4 w1 = *(const float4*)&Ws[(kk+1)*128 + jj];
      float4 w2 = *(const float4*)&Ws[(kk+2)*128 + jj];
      float4 w3 = *(const float4*)&Ws[(kk+3)*128 + jj];
      #pragma unroll
      for (int rr = 0; rr < RPT; ++rr) {
        float4 xq = *(const float4*)&Xs[(r0+rr)*128 + kc + kk];
        FMA4(acc[rr], xq.x, w0);
        FMA4(acc[rr], xq.y, w1);
        FMA4(acc[rr], xq.z, w2);
        FMA4(acc[rr], xq.w, w3);
      }
    }
  }
}

// ---------------- K3: OUT1 = wh @ [ea|wa|whh_w]^T, OUT2 = th @ [...], + WBV/TBV ----
__global__ __launch_bounds__(256) void k3_gemm1(float* __restrict__ ws)
{
  __shared__ float Xs[32*128];
  __shared__ float Wsh[32*128];
  int bid = blockIdx.x, tid = threadIdx.x;
  const int tc = tid & 31, tr = tid >> 5;
  const int jj = tc*4, r0 = tr*4;
  float4 acc[4];
  if (bid < 640) {
    int side = bid >= 320;
    int b2 = bid - (side ? 320 : 0);
    int rt = b2 & 63, ct = b2 >> 6;      // 64 row tiles x 5 col tiles
    int row0 = rt*32;
    stage_x_direct(Xs, ws + (side ? TH_OFF : WH_OFF), row0, tid);
    gemm_core2<4,256>(ws + (side ? WT2_OFF : WT1_OFF), 640, ct*128, Xs, Wsh, tid, acc);
    float* C = ws + (side ? OUT2_OFF : OUT1_OFF);
    #pragma unroll
    for (int rr = 0; rr < 4; ++rr)
      *(float4*)&C[(row0+r0+rr)*640 + ct*128 + jj] = acc[rr];
  } else {
    int which = bid - 640;               // 0: WBV = THS@wb^T, 1: TBV = WHS@tb^T
    stage_x_direct(Xs, ws + (which ? WHS_OFF : THS_OFF), 0, tid);
    gemm_core2<4,256>(ws + (which ? TBT_OFF : WBT_OFF), 128, 0, Xs, Wsh, tid, acc);
    float* C = ws + (which ? TBV_OFF : WBV_OFF);
    #pragma unroll
    for (int rr = 0; rr < 4; ++rr)
      *(float4*)&C[(r0+rr)*128 + jj] = acc[rr];
  }
}

// ---------------- K4: edge tanh + both edge sums (512 blocks, LDS-staged Bt) -------
__global__ __launch_bounds__(256) void k4_edge(
    const float* __restrict__ ef, float* __restrict__ ws, float* __restrict__ out)
{
  __shared__ float Bs[64*128];     // Bt slice for this bp
  __shared__ float e_lds[4*64];
  __shared__ float red[2][4][128];
  int bid = blockIdx.x, tid = threadIdx.x;
  int bp = bid >> 4, wq = bid & 15;        // 4 w's per block
  int j = tid & 127, tsel = tid >> 7;
  float v1j = ws[V1_OFF + j], c0j = ws[C0_OFF + j];
  // stage Bt (OUT2 rows bp*64..+64, first 128 cols)
  {
    const float* o2 = ws + OUT2_OFF + bp*64*640;
    #pragma unroll
    for (int q = 0; q < 8; ++q) {
      int idx = q*256 + tid;
      int t = idx >> 5, jq = (idx & 31)*4;
      *(float4*)&Bs[t*128 + jq] = *(const float4*)&o2[t*640 + jq];
    }
  }
  if (tid < 64) {
    int w = tid >> 4, t4 = (tid & 15)*4;
    *(float4*)&e_lds[w*64 + t4] = *(const float4*)&ef[bp*4096 + (wq*4 + w)*64 + t4];
  }
  float a_reg[4];
  #pragma unroll
  for (int w = 0; w < 4; ++w)
    a_reg[w] = ws[OUT1_OFF + (bp*64 + wq*4 + w)*640 + j];
  __syncthreads();
  float tsum[4] = {0.f, 0.f, 0.f, 0.f};
  float* edst = out + 524288 + (bp*64 + wq*4)*8192 + j;   // + w*8192 + t*128
  float* pdst = ws + ESTP_OFF + wq*(NR*H) + bp*64*128 + j;
  for (int i = 0; i < 32; ++i) {
    int t = 2*i + tsel;
    float base = Bs[t*128 + j] + c0j;
    float wsum = 0.f;
    #pragma unroll
    for (int w = 0; w < 4; ++w) {
      float ev = e_lds[w*64 + t];
      float pre = a_reg[w] + fmaf(ev, v1j, base);
      float hv = fast_tanh(pre);
      edst[w*8192 + t*128] = hv;
      tsum[w] += hv;
      wsum += hv;
    }
    pdst[t*128] = wsum;
  }
  #pragma unroll
  for (int w = 0; w < 4; ++w) red[tsel][w][j] = tsum[w];
  __syncthreads();
  if (tsel == 0) {
    #pragma unroll
    for (int w = 0; w < 4; ++w)
      ws[ESW_OFF + (bp*64 + wq*4 + w)*128 + j] = red[0][w][j] + red[1][w][j];
  }
}

// ---------------- K5: fused msgs -> gi -> GRU gates -> out ----------------
__global__ __launch_bounds__(512) void k5_fused(
    float* __restrict__ ws, float* __restrict__ out,
    const float* __restrict__ wm_b, const float* __restrict__ tm_b,
    const float* __restrict__ bih_w, const float* __restrict__ bhh_w,
    const float* __restrict__ bih_t, const float* __restrict__ bhh_t)
{
  __shared__ float Xs[16*128];
  __shared__ float Wsh[32*128];
  int bid = blockIdx.x, tid = threadIdx.x;
  int side = bid >> 7, rt = bid & 127;
  int row0 = rt*16;
  const int tc = tid & 31, tr = tid >> 5;   // tr 0..15
  const int jj = tc*4;
  // stage X (ESW for side 0, sum of 16 ESTP partials for side 1)
  {
    int r = tid >> 5, jq = (tid & 31)*4;
    float4 v;
    if (side == 0) {
      v = *(const float4*)&ws[ESW_OFF + (row0+r)*128 + jq];
    } else {
      v = *(const float4*)&ws[ESTP_OFF + (row0+r)*128 + jq];
      #pragma unroll
      for (int p = 1; p < 16; ++p) {
        float4 u = *(const float4*)&ws[ESTP_OFF + p*(NR*H) + (row0+r)*128 + jq];
        v.x += u.x; v.y += u.y; v.z += u.z; v.w += u.w;
      }
    }
    *(float4*)&Xs[r*128 + jq] = v;
  }
  float4 accm[1];
  gemm_core2<1,512>(ws + (side ? TCT_OFF : WCT_OFF), 128, 0, Xs, Wsh, tid, accm);
  __syncthreads();
  // msgs epilogue -> Xs
  {
    const float* OUTx = ws + (side ? OUT2_OFF : OUT1_OFF);
    const float* BV   = ws + (side ? TBV_OFF : WBV_OFF);
    const float* mb   = side ? tm_b : wm_b;
    float4 b4 = *(const float4*)&mb[jj];
    int n = row0 + tr;
    float4 wa4 = *(const float4*)&OUTx[n*640 + 128 + jj];
    float4 bv4 = *(const float4*)&BV[(n >> 6)*128 + jj];
    float4 r;
    r.x = accm[0].x + 64.f*(wa4.x + b4.x) + bv4.x;
    r.y = accm[0].y + 64.f*(wa4.y + b4.y) + bv4.y;
    r.z = accm[0].z + 64.f*(wa4.z + b4.z) + bv4.z;
    r.w = accm[0].w + 64.f*(wa4.w + b4.w) + bv4.w;
    __syncthreads();
    *(float4*)&Xs[tr*128 + jj] = r;
  }
  __syncthreads();
  const float* WIH = ws + (side ? WIHTT_OFF : WIHWT_OFF);
  float4 accr[1], accz[1], accn[1];
  gemm_core2<1,512>(WIH, 384, 0,   Xs, Wsh, tid, accr);
  gemm_core2<1,512>(WIH, 384, 128, Xs, Wsh, tid, accz);
  gemm_core2<1,512>(WIH, 384, 256, Xs, Wsh, tid, accn);
  // GRU epilogue
  {
    const float* OUTx = ws + (side ? OUT2_OFF : OUT1_OFF);
    const float* Hsrc = ws + (side ? TH_OFF : WH_OFF);
    const float* bi = side ? bih_t : bih_w;
    const float* bh = side ? bhh_t : bhh_w;
    float4 bir = *(const float4*)&bi[jj];
    float4 biz = *(const float4*)&bi[128 + jj];
    float4 bin = *(const float4*)&bi[256 + jj];
    float4 bhr = *(const float4*)&bh[jj];
    float4 bhz = *(const float4*)&bh[128 + jj];
    float4 bhn = *(const float4*)&bh[256 + jj];
    int n = row0 + tr;
    float4 ghr = *(const float4*)&OUTx[n*640 + 256 + jj];
    float4 ghz = *(const float4*)&OUTx[n*640 + 384 + jj];
    float4 ghn = *(const float4*)&OUTx[n*640 + 512 + jj];
    float4 h4  = *(const float4*)&Hsrc[n*128 + jj];
    float4 o;
    {
      float r = fast_sigmoid(accr[0].x + bir.x + ghr.x + bhr.x);
      float z = fast_sigmoid(accz[0].x + biz.x + ghz.x + bhz.x);
      float nn = fast_tanh(accn[0].x + bin.x + r*(ghn.x + bhn.x));
      o.x = (1.f - z)*nn + z*h4.x;
    }
    {
      float r = fast_sigmoid(accr[0].y + bir.y + ghr.y + bhr.y);
      float z = fast_sigmoid(accz[0].y + biz.y + ghz.y + bhz.y);
      float nn = fast_tanh(accn[0].y + bin.y + r*(ghn.y + bhn.y));
      o.y = (1.f - z)*nn + z*h4.y;
    }
    {
      float r = fast_sigmoid(accr[0].z + bir.z + ghr.z + bhr.z);
      float z = fast_sigmoid(accz[0].z + biz.z + ghz.z + bhz.z);
      float nn = fast_tanh(accn[0].z + bin.z + r*(ghn.z + bhn.z));
      o.z = (1.f - z)*nn + z*h4.z;
    }
    {
      float r = fast_sigmoid(accr[0].w + bir.w + ghr.w + bhr.w);
      float z = fast_sigmoid(accz[0].w + biz.w + ghz.w + bhz.w);
      float nn = fast_tanh(accn[0].w + bin.w + r*(ghn.w + bhn.w));
      o.w = (1.f - z)*nn + z*h4.w;
    }
    *(float4*)&out[side*262144 + n*128 + jj] = o;
  }
}

extern "C" void kernel_launch(void* const* d_in, const int* in_sizes, int n_in,
                              void* d_out, int out_size, void* d_ws, size_t ws_size,
                              hipStream_t stream)
{
  const float* wf    = (const float*)d_in[0];
  const float* tf    = (const float*)d_in[1];
  const float* ef    = (const float*)d_in[2];
  const float* wp_w  = (const float*)d_in[3];
  const float* wp_b  = (const float*)d_in[4];
  const float* tp_w  = (const float*)d_in[5];
  const float* tp_b  = (const float*)d_in[6];
  const float* ep_w  = (const float*)d_in[7];
  const float* ep_b  = (const float*)d_in[8];
  const float* eu_w  = (const float*)d_in[9];
  const float* eu_b  = (const float*)d_in[10];
  const float* wm_w  = (const float*)d_in[11];
  const float* wm_b  = (const float*)d_in[12];
  const float* tm_w  = (const float*)d_in[13];
  const float* tm_b  = (const float*)d_in[14];
  const float* wih_w = (const float*)d_in[15];
  const float* whh_w = (const float*)d_in[16];
  const float* bih_w = (const float*)d_in[17];
  const float* bhh_w = (const float*)d_in[18];
  const float* wih_t = (const float*)d_in[19];
  const float* whh_t = (const float*)d_in[20];
  const float* bih_t = (const float*)d_in[21];
  const float* bhh_t = (const float*)d_in[22];
  float* ws  = (float*)d_ws;
  float* out = (float*)d_out;

  hipLaunchKernelGGL(k1_proj_transpose, dim3(3329), dim3(256), 0, stream,
                     wf, tf, wp_w, wp_b, tp_w, tp_b, eu_w, wm_w, tm_w,
                     whh_w, whh_t, wih_w, wih_t, ep_w, ep_b, eu_b, ws);
  hipLaunchKernelGGL(k3_gemm1, dim3(642),  dim3(256), 0, stream, ws);
  hipLaunchKernelGGL(k4_edge,  dim3(512),  dim3(256), 0, stream, ef, ws, out);
  hipLaunchKernelGGL(k5_fused, dim3(256),  dim3(512), 0, stream, ws, out,
                     wm_b, tm_b, bih_w, bhh_w, bih_t, bhh_t);
}

// Round 3
// 189.200 us; speedup vs baseline: 1.5602x; 1.5602x over previous
//
#include <hip/hip_runtime.h>

#define DEV __device__ __forceinline__

constexpr int H  = 128;
constexpr int BP = 32;        // B*P
constexpr int NR = 2048;      // BP*64 rows

// workspace layout (float offsets)
constexpr int WH_OFF    = 0;                       // [2048][128] weapon_h
constexpr int TH_OFF    = WH_OFF + NR*H;           // [2048][128] target_h
constexpr int WHS_OFF   = TH_OFF + NR*H;           // [32][128] weapon_h.sum(axis=2)
constexpr int THS_OFF   = WHS_OFF + BP*H;          // [32][128]
constexpr int V1_OFF    = THS_OFF + BP*H;          // [128]
constexpr int C0_OFF    = V1_OFF + H;              // [128]
constexpr int WT1_OFF   = C0_OFF + H;              // [128][640]  eaT|waT|whh_wT
constexpr int WT2_OFF   = WT1_OFF + 128*640;       // [128][640]  ebT|taT|whh_tT
constexpr int WCT_OFF   = WT2_OFF + 128*640;       // [128][128]
constexpr int TCT_OFF   = WCT_OFF + 128*128;
constexpr int WIHWT_OFF = TCT_OFF + 128*128;       // [128][384]
constexpr int WIHTT_OFF = WIHWT_OFF + 128*384;
constexpr int WBT_OFF   = WIHTT_OFF + 128*384;     // [128][128]
constexpr int TBT_OFF   = WBT_OFF + 128*128;
constexpr int OUT1_OFF  = TBT_OFF + 128*128;       // [2048][640]  A|WA|ghw
constexpr int OUT2_OFF  = OUT1_OFF + NR*640;       // [2048][640]  Bt|TA|ght
constexpr int ESW_OFF   = OUT2_OFF + NR*640;       // [2048][128] edge sum over t
constexpr int ESTP_OFF  = ESW_OFF + NR*H;          // [16][2048][128] partial sums over w
constexpr int MSGW_OFF  = ESTP_OFF + 16*NR*H;      // [2048][128]
constexpr int MSGT_OFF  = MSGW_OFF + NR*H;
constexpr int GIW_OFF   = MSGT_OFF + NR*H;         // [2048][384]
constexpr int GIT_OFF   = GIW_OFF + NR*384;
constexpr int WBV_OFF   = GIT_OFF + NR*384;        // [32][128]
constexpr int TBV_OFF   = WBV_OFF + BP*H;          // [32][128]

DEV float fast_tanh(float x) {
  float e = __builtin_amdgcn_exp2f(x * 2.8853900817779268f);  // exp(2x)
  return fmaf(-2.0f, __builtin_amdgcn_rcpf(e + 1.0f), 1.0f);
}
DEV float fast_sigmoid(float x) {
  float e = __builtin_amdgcn_exp2f(x * -1.4426950408889634f); // exp(-x)
  return __builtin_amdgcn_rcpf(1.0f + e);
}

// ---------------- K0: weight transposes, LDS-tiled, coalesced both sides ----------
__global__ __launch_bounds__(256) void k0_transpose(
    const float* __restrict__ eu_w, const float* __restrict__ wm_w,
    const float* __restrict__ tm_w,
    const float* __restrict__ whh_w, const float* __restrict__ whh_t,
    const float* __restrict__ wih_w, const float* __restrict__ wih_t,
    float* __restrict__ ws)
{
  __shared__ float T[128*133];
  int tt = blockIdx.x, tid = threadIdx.x;
  const float* src; int rs = 384, co = 0, row0 = 0, dsto, ldd, j0;
  switch (tt) {
    case 0:  src=eu_w;  dsto=WT1_OFF; ldd=640; j0=0;   break;
    case 1:  src=wm_w;  dsto=WT1_OFF; ldd=640; j0=128; break;
    case 2: case 3: case 4:
      src=whh_w; rs=128; row0=(tt-2)*128; dsto=WT1_OFF; ldd=640; j0=256+(tt-2)*128; break;
    case 5:  src=eu_w;  co=128; dsto=WT2_OFF; ldd=640; j0=0; break;
    case 6:  src=tm_w;  dsto=WT2_OFF; ldd=640; j0=128; break;
    case 7: case 8: case 9:
      src=whh_t; rs=128; row0=(tt-7)*128; dsto=WT2_OFF; ldd=640; j0=256+(tt-7)*128; break;
    case 10: src=wm_w; co=256; dsto=WCT_OFF; ldd=128; j0=0; break;
    case 11: src=tm_w; co=256; dsto=TCT_OFF; ldd=128; j0=0; break;
    case 12: src=wm_w; co=128; dsto=WBT_OFF; ldd=128; j0=0; break;
    case 13: src=tm_w; co=128; dsto=TBT_OFF; ldd=128; j0=0; break;
    case 14: case 15: case 16:
      src=wih_w; rs=128; row0=(tt-14)*128; dsto=WIHWT_OFF; ldd=384; j0=(tt-14)*128; break;
    default:
      src=wih_t; rs=128; row0=(tt-17)*128; dsto=WIHTT_OFF; ldd=384; j0=(tt-17)*128; break;
  }
  #pragma unroll
  for (int q = 0; q < 16; ++q) {
    int idx = q*1024 + tid*4;
    int r = idx >> 7, c = idx & 127;
    float4 v = *(const float4*)&src[(row0 + r)*rs + co + c];
    float* t = &T[r*133 + c];
    t[0]=v.x; t[1]=v.y; t[2]=v.z; t[3]=v.w;
  }
  __syncthreads();
  float* dst = ws + dsto;
  #pragma unroll
  for (int q = 0; q < 64; ++q) {
    int idx = q*256 + tid;
    int k = idx >> 7, j = idx & 127;
    dst[k*ldd + j0 + j] = T[j*133 + k];
  }
}

// ---------------- K1: projections + per-(b,p) sums + v1/c0 ----------------
__global__ __launch_bounds__(256) void k1_proj(
    const float* __restrict__ wf, const float* __restrict__ tf,
    const float* __restrict__ wp_w, const float* __restrict__ wp_b,
    const float* __restrict__ tp_w, const float* __restrict__ tp_b,
    const float* __restrict__ eu_w,
    const float* __restrict__ ep_w, const float* __restrict__ ep_b,
    const float* __restrict__ eu_b,
    float* __restrict__ ws)
{
  __shared__ float fs[2][32][4];
  int bid = blockIdx.x, tid = threadIdx.x;
  if (bid < 2048) {
    int gid = bid*256 + tid;
    int m = gid >> 7;       // 0..4095
    int j = gid & 127;
    int side = m >> 11;
    int n = m & 2047;
    const float* F  = side ? tf : wf;
    const float* Pw = side ? tp_w : wp_w;
    const float* Pb = side ? tp_b : wp_b;
    float4 x  = *(const float4*)&F[n*4];
    float4 wv = *(const float4*)&Pw[j*4];
    float v = x.x*wv.x + x.y*wv.y + x.z*wv.z + x.w*wv.w + Pb[j];
    ws[(side ? TH_OFF : WH_OFF) + n*H + j] = v;
  } else {
    // sums block: feature sums -> WHS/THS, plus v1/c0
    {
      int side = tid >> 7, r = tid & 127;
      int bp = r >> 2, c = r & 3;
      const float* F = side ? tf : wf;
      float s = 0.f;
      #pragma unroll 8
      for (int w = 0; w < 64; ++w) s += F[bp*256 + w*4 + c];
      fs[side][bp][c] = s;
    }
    __syncthreads();
    {
      int side = tid >> 7, j = tid & 127;
      const float* Pw = side ? tp_w : wp_w;
      const float* Pb = side ? tp_b : wp_b;
      float4 wv = *(const float4*)&Pw[j*4];
      float pb = Pb[j] * 64.f;
      float* dst = ws + (side ? THS_OFF : WHS_OFF) + j;
      #pragma unroll 4
      for (int bp = 0; bp < 32; ++bp) {
        float4 f = *(const float4*)&fs[side][bp][0];
        dst[bp*128] = f.x*wv.x + f.y*wv.y + f.z*wv.z + f.w*wv.w + pb;
      }
    }
    if (tid < 128) {
      int j = tid;
      float s1 = 0.f, s0 = 0.f;
      for (int k = 0; k < 128; ++k) {
        float ec = eu_w[j*384 + 256 + k];
        s1 = fmaf(ec, ep_w[k], s1);
        s0 = fmaf(ec, ep_b[k], s0);
      }
      ws[V1_OFF + j] = s1;
      ws[C0_OFF + j] = s0 + eu_b[j];
    }
  }
}

// ---------------- generic 32x128-tile fp32 GEMM core (K=128) ----------------
#define FMA4(A, s, Wv) do { A.x = fmaf(s, Wv.x, A.x); A.y = fmaf(s, Wv.y, A.y); \
                            A.z = fmaf(s, Wv.z, A.z); A.w = fmaf(s, Wv.w, A.w); } while (0)

DEV void stage_x_direct(float* Xs, const float* __restrict__ X, int row0, int tid) {
  const float* src = X + row0*128;
  #pragma unroll
  for (int q = 0; q < 4; ++q) {
    int idx = q*1024 + tid*4;
    *(float4*)&Xs[idx] = *(const float4*)&src[idx];
  }
}

DEV void stage_x_sum16(float* Xs, const float* __restrict__ base, int row0, int tid) {
  #pragma unroll
  for (int q = 0; q < 4; ++q) {
    int idx = q*1024 + tid*4;
    float4 s = *(const float4*)&base[row0*128 + idx];
    #pragma unroll
    for (int wt = 1; wt < 16; ++wt) {
      float4 v = *(const float4*)&base[wt*(NR*H) + row0*128 + idx];
      s.x += v.x; s.y += v.y; s.z += v.z; s.w += v.w;
    }
    *(float4*)&Xs[idx] = s;
  }
}

DEV void gemm_core(const float* __restrict__ Wt, int ldw, int j0,
                   const float* Xs, float* Ws, int tid, float4 acc[4])
{
  const int tc = tid & 31, tr = tid >> 5;
  const int jj = tc*4, r0 = tr*4;
  #pragma unroll
  for (int i = 0; i < 4; ++i) acc[i] = make_float4(0.f, 0.f, 0.f, 0.f);
  for (int kc = 0; kc < 128; kc += 32) {
    __syncthreads();
    #pragma unroll
    for (int q = 0; q < 4; ++q) {
      int idx = q*1024 + tid*4;
      int kk = idx >> 7, j = idx & 127;
      *(float4*)&Ws[idx] = *(const float4*)&Wt[(kc+kk)*ldw + j0 + j];
    }
    __syncthreads();
    #pragma unroll
    for (int kk = 0; kk < 32; kk += 4) {
      float4 w0 = *(const float4*)&Ws[(kk+0)*128 + jj];
      float4 w1 = *(const float4*)&Ws[(kk+1)*128 + jj];
      float4 w2 = *(const float4*)&Ws[(kk+2)*128 + jj];
      float4 w3 = *(const float4*)&Ws[(kk+3)*128 + jj];
      #pragma unroll
      for (int rr = 0; rr < 4; ++rr) {
        float4 xq = *(const float4*)&Xs[(r0+rr)*128 + kc + kk];
        FMA4(acc[rr], xq.x, w0);
        FMA4(acc[rr], xq.y, w1);
        FMA4(acc[rr], xq.z, w2);
        FMA4(acc[rr], xq.w, w3);
      }
    }
  }
}

// ---------------- K3: OUT1 = wh @ [ea|wa|whh_w]^T, OUT2 = th @ [...], + WBV/TBV ----
__global__ __launch_bounds__(256) void k3_gemm1(float* __restrict__ ws)
{
  __shared__ float Xs[32*128];
  __shared__ float Wsh[32*128];
  int bid = blockIdx.x, tid = threadIdx.x;
  const int tc = tid & 31, tr = tid >> 5;
  const int jj = tc*4, r0 = tr*4;
  float4 acc[4];
  if (bid < 640) {
    int side = bid >= 320;
    int b2 = bid - (side ? 320 : 0);
    int rt = b2 & 63, ct = b2 >> 6;      // 64 row tiles x 5 col tiles
    int row0 = rt*32;
    stage_x_direct(Xs, ws + (side ? TH_OFF : WH_OFF), row0, tid);
    gemm_core(ws + (side ? WT2_OFF : WT1_OFF), 640, ct*128, Xs, Wsh, tid, acc);
    float* C = ws + (side ? OUT2_OFF : OUT1_OFF);
    #pragma unroll
    for (int rr = 0; rr < 4; ++rr)
      *(float4*)&C[(row0+r0+rr)*640 + ct*128 + jj] = acc[rr];
  } else {
    int which = bid - 640;               // 0: WBV = THS@wb^T, 1: TBV = WHS@tb^T
    stage_x_direct(Xs, ws + (which ? WHS_OFF : THS_OFF), 0, tid);
    gemm_core(ws + (which ? TBT_OFF : WBT_OFF), 128, 0, Xs, Wsh, tid, acc);
    float* C = ws + (which ? TBV_OFF : WBV_OFF);
    #pragma unroll
    for (int rr = 0; rr < 4; ++rr)
      *(float4*)&C[(r0+rr)*128 + jj] = acc[rr];
  }
}

// ---------------- K4: edge tanh + both edge sums (512 blocks, LDS-staged Bt) -------
__global__ __launch_bounds__(256) void k4_edge(
    const float* __restrict__ ef, float* __restrict__ ws, float* __restrict__ out)
{
  __shared__ float Bs[64*128];     // Bt slice for this bp
  __shared__ float e_lds[4*64];
  __shared__ float red[2][4][128];
  int bid = blockIdx.x, tid = threadIdx.x;
  int bp = bid >> 4, wq = bid & 15;        // 4 w's per block
  int j = tid & 127, tsel = tid >> 7;
  float v1j = ws[V1_OFF + j], c0j = ws[C0_OFF + j];
  // stage Bt (OUT2 rows bp*64..+64, first 128 cols)
  {
    const float* o2 = ws + OUT2_OFF + bp*64*640;
    #pragma unroll
    for (int q = 0; q < 8; ++q) {
      int idx = q*256 + tid;
      int t = idx >> 5, jq = (idx & 31)*4;
      *(float4*)&Bs[t*128 + jq] = *(const float4*)&o2[t*640 + jq];
    }
  }
  if (tid < 64) {
    int w = tid >> 4, t4 = (tid & 15)*4;
    *(float4*)&e_lds[w*64 + t4] = *(const float4*)&ef[bp*4096 + (wq*4 + w)*64 + t4];
  }
  float a_reg[4];
  #pragma unroll
  for (int w = 0; w < 4; ++w)
    a_reg[w] = ws[OUT1_OFF + (bp*64 + wq*4 + w)*640 + j];
  __syncthreads();
  float tsum[4] = {0.f, 0.f, 0.f, 0.f};
  float* edst = out + 524288 + (bp*64 + wq*4)*8192 + j;   // + w*8192 + t*128
  float* pdst = ws + ESTP_OFF + wq*(NR*H) + bp*64*128 + j;
  for (int i = 0; i < 32; ++i) {
    int t = 2*i + tsel;
    float base = Bs[t*128 + j] + c0j;
    float wsum = 0.f;
    #pragma unroll
    for (int w = 0; w < 4; ++w) {
      float ev = e_lds[w*64 + t];
      float pre = a_reg[w] + fmaf(ev, v1j, base);
      float hv = fast_tanh(pre);
      __builtin_nontemporal_store(hv, &edst[w*8192 + t*128]);
      tsum[w] += hv;
      wsum += hv;
    }
    pdst[t*128] = wsum;
  }
  #pragma unroll
  for (int w = 0; w < 4; ++w) red[tsel][w][j] = tsum[w];
  __syncthreads();
  if (tsel == 0) {
    #pragma unroll
    for (int w = 0; w < 4; ++w)
      ws[ESW_OFF + (bp*64 + wq*4 + w)*128 + j] = red[0][w][j] + red[1][w][j];
  }
}

// ---------------- K5: msgs = edge_sum @ wc^T + T*WA + WBv + T*bias ----------------
__global__ __launch_bounds__(256) void k5_gemm2(
    float* __restrict__ ws, const float* __restrict__ wm_b, const float* __restrict__ tm_b)
{
  __shared__ float Xs[32*128];
  __shared__ float Wsh[32*128];
  int bid = blockIdx.x, tid = threadIdx.x;
  int side = bid >> 6, rt = bid & 63;
  int row0 = rt*32;
  const int tc = tid & 31, tr = tid >> 5;
  const int jj = tc*4, r0 = tr*4;
  if (side == 0) stage_x_direct(Xs, ws + ESW_OFF, row0, tid);
  else           stage_x_sum16(Xs, ws + ESTP_OFF, row0, tid);
  float4 acc[4];
  gemm_core(ws + (side ? TCT_OFF : WCT_OFF), 128, 0, Xs, Wsh, tid, acc);
  const float* OUTx = ws + (side ? OUT2_OFF : OUT1_OFF);
  const float* BV   = ws + (side ? TBV_OFF : WBV_OFF);
  const float* mb   = side ? tm_b : wm_b;
  float* MSG        = ws + (side ? MSGT_OFF : MSGW_OFF);
  float4 b4 = *(const float4*)&mb[jj];
  #pragma unroll
  for (int rr = 0; rr < 4; ++rr) {
    int n = row0 + r0 + rr;
    float4 wa4 = *(const float4*)&OUTx[n*640 + 128 + jj];
    float4 bv4 = *(const float4*)&BV[(n >> 6)*128 + jj];
    float4 r;
    r.x = acc[rr].x + 64.f*(wa4.x + b4.x) + bv4.x;
    r.y = acc[rr].y + 64.f*(wa4.y + b4.y) + bv4.y;
    r.z = acc[rr].z + 64.f*(wa4.z + b4.z) + bv4.z;
    r.w = acc[rr].w + 64.f*(wa4.w + b4.w) + bv4.w;
    *(float4*)&MSG[n*128 + jj] = r;
  }
}

// ---------------- K6: gi = msgs @ w_ih^T ----------------
__global__ __launch_bounds__(256) void k6_gemm3(float* __restrict__ ws)
{
  __shared__ float Xs[32*128];
  __shared__ float Wsh[32*128];
  int bid = blockIdx.x, tid = threadIdx.x;
  int side = bid >= 192;
  int b2 = bid - (side ? 192 : 0);
  int rt = b2 & 63, ct = b2 >> 6;       // 64 row tiles x 3 col tiles
  int row0 = rt*32;
  const int tc = tid & 31, tr = tid >> 5;
  const int jj = tc*4, r0 = tr*4;
  stage_x_direct(Xs, ws + (side ? MSGT_OFF : MSGW_OFF), row0, tid);
  float4 acc[4];
  gemm_core(ws + (side ? WIHTT_OFF : WIHWT_OFF), 384, ct*128, Xs, Wsh, tid, acc);
  float* C = ws + (side ? GIT_OFF : GIW_OFF);
  #pragma unroll
  for (int rr = 0; rr < 4; ++rr)
    *(float4*)&C[(row0+r0+rr)*384 + ct*128 + jj] = acc[rr];
}

// ---------------- K7: GRU gates (elementwise) ----------------
__global__ __launch_bounds__(256) void k7_gru(
    const float* __restrict__ ws, float* __restrict__ out,
    const float* __restrict__ bih_w, const float* __restrict__ bhh_w,
    const float* __restrict__ bih_t, const float* __restrict__ bhh_t)
{
  int gid = blockIdx.x*256 + threadIdx.x;
  int m = gid >> 7, j = gid & 127;
  int side = m >> 11, n = m & 2047;
  const float* GI = ws + (side ? GIT_OFF : GIW_OFF) + n*384;
  const float* GH = ws + (side ? OUT2_OFF : OUT1_OFF) + n*640 + 256;
  const float* Hv = ws + (side ? TH_OFF : WH_OFF) + n*128;
  const float* bi = side ? bih_t : bih_w;
  const float* bh = side ? bhh_t : bhh_w;
  float gir = GI[j]       + bi[j];
  float giz = GI[128 + j] + bi[128 + j];
  float gin = GI[256 + j] + bi[256 + j];
  float ghr = GH[j]       + bh[j];
  float ghz = GH[128 + j] + bh[128 + j];
  float ghn = GH[256 + j] + bh[256 + j];
  float r  = fast_sigmoid(gir + ghr);
  float z  = fast_sigmoid(giz + ghz);
  float nn = fast_tanh(gin + r*ghn);
  float h  = Hv[j];
  out[side*262144 + n*128 + j] = (1.f - z)*nn + z*h;
}

extern "C" void kernel_launch(void* const* d_in, const int* in_sizes, int n_in,
                              void* d_out, int out_size, void* d_ws, size_t ws_size,
                              hipStream_t stream)
{
  const float* wf    = (const float*)d_in[0];
  const float* tf    = (const float*)d_in[1];
  const float* ef    = (const float*)d_in[2];
  const float* wp_w  = (const float*)d_in[3];
  const float* wp_b  = (const float*)d_in[4];
  const float* tp_w  = (const float*)d_in[5];
  const float* tp_b  = (const float*)d_in[6];
  const float* ep_w  = (const float*)d_in[7];
  const float* ep_b  = (const float*)d_in[8];
  const float* eu_w  = (const float*)d_in[9];
  const float* eu_b  = (const float*)d_in[10];
  const float* wm_w  = (const float*)d_in[11];
  const float* wm_b  = (const float*)d_in[12];
  const float* tm_w  = (const float*)d_in[13];
  const float* tm_b  = (const float*)d_in[14];
  const float* wih_w = (const float*)d_in[15];
  const float* whh_w = (const float*)d_in[16];
  const float* bih_w = (const float*)d_in[17];
  const float* bhh_w = (const float*)d_in[18];
  const float* wih_t = (const float*)d_in[19];
  const float* whh_t = (const float*)d_in[20];
  const float* bih_t = (const float*)d_in[21];
  const float* bhh_t = (const float*)d_in[22];
  float* ws  = (float*)d_ws;
  float* out = (float*)d_out;

  hipLaunchKernelGGL(k0_transpose, dim3(20), dim3(256), 0, stream,
                     eu_w, wm_w, tm_w, whh_w, whh_t, wih_w, wih_t, ws);
  hipLaunchKernelGGL(k1_proj, dim3(2049), dim3(256), 0, stream,
                     wf, tf, wp_w, wp_b, tp_w, tp_b, eu_w, ep_w, ep_b, eu_b, ws);
  hipLaunchKernelGGL(k3_gemm1, dim3(642),  dim3(256), 0, stream, ws);
  hipLaunchKernelGGL(k4_edge,  dim3(512),  dim3(256), 0, stream, ef, ws, out);
  hipLaunchKernelGGL(k5_gemm2, dim3(128),  dim3(256), 0, stream, ws, wm_b, tm_b);
  hipLaunchKernelGGL(k6_gemm3, dim3(384),  dim3(256), 0, stream, ws);
  hipLaunchKernelGGL(k7_gru,   dim3(2048), dim3(256), 0, stream, ws, out,
                     bih_w, bhh_w, bih_t, bhh_t);
}

// Round 5
// 186.575 us; speedup vs baseline: 1.5821x; 1.0141x over previous
//
#include <hip/hip_runtime.h>

#define DEV __device__ __forceinline__

constexpr int H  = 128;
constexpr int BP = 32;        // B*P
constexpr int NR = 2048;      // BP*64 rows

// workspace layout (float offsets)
constexpr int WH_OFF    = 0;                       // [2048][128] weapon_h
constexpr int TH_OFF    = WH_OFF + NR*H;           // [2048][128] target_h
constexpr int WHS_OFF   = TH_OFF + NR*H;           // [32][128] weapon_h.sum(axis=2)
constexpr int THS_OFF   = WHS_OFF + BP*H;          // [32][128]
constexpr int V1_OFF    = THS_OFF + BP*H;          // [128]
constexpr int C0_OFF    = V1_OFF + H;              // [128]
constexpr int WT1_OFF   = C0_OFF + H;              // [128][640]  eaT|waT|whh_wT
constexpr int WT2_OFF   = WT1_OFF + 128*640;       // [128][640]  ebT|taT|whh_tT
constexpr int WCT_OFF   = WT2_OFF + 128*640;       // [128][128]
constexpr int TCT_OFF   = WCT_OFF + 128*128;
constexpr int WIHWT_OFF = TCT_OFF + 128*128;       // [128][384]
constexpr int WIHTT_OFF = WIHWT_OFF + 128*384;
constexpr int WBT_OFF   = WIHTT_OFF + 128*384;     // [128][128]
constexpr int TBT_OFF   = WBT_OFF + 128*128;
constexpr int OUT1_OFF  = TBT_OFF + 128*128;       // [2048][640]  A|WA|ghw
constexpr int OUT2_OFF  = OUT1_OFF + NR*640;       // [2048][640]  Bt|TA|ght
constexpr int ESW_OFF   = OUT2_OFF + NR*640;       // [2048][128] edge sum over t
constexpr int ESTP_OFF  = ESW_OFF + NR*H;          // [8][2048][128] partial sums over w
constexpr int MSGW_OFF  = ESTP_OFF + 8*NR*H;       // [2048][128]
constexpr int MSGT_OFF  = MSGW_OFF + NR*H;
constexpr int GIW_OFF   = MSGT_OFF + NR*H;         // [2048][384]
constexpr int GIT_OFF   = GIW_OFF + NR*384;
constexpr int WBV_OFF   = GIT_OFF + NR*384;        // [32][128]
constexpr int TBV_OFF   = WBV_OFF + BP*H;          // [32][128]

DEV float fast_tanh(float x) {
  float e = __builtin_amdgcn_exp2f(x * 2.8853900817779268f);  // exp(2x)
  return fmaf(-2.0f, __builtin_amdgcn_rcpf(e + 1.0f), 1.0f);
}
DEV float fast_sigmoid(float x) {
  float e = __builtin_amdgcn_exp2f(x * -1.4426950408889634f); // exp(-x)
  return __builtin_amdgcn_rcpf(1.0f + e);
}

// ---------------- KA: projections + sums + v1/c0 + weight transposes ----------------
__global__ __launch_bounds__(256) void ka_prep(
    const float* __restrict__ wf, const float* __restrict__ tf,
    const float* __restrict__ wp_w, const float* __restrict__ wp_b,
    const float* __restrict__ tp_w, const float* __restrict__ tp_b,
    const float* __restrict__ eu_w, const float* __restrict__ wm_w,
    const float* __restrict__ tm_w,
    const float* __restrict__ whh_w, const float* __restrict__ whh_t,
    const float* __restrict__ wih_w, const float* __restrict__ wih_t,
    const float* __restrict__ ep_w, const float* __restrict__ ep_b,
    const float* __restrict__ eu_b,
    float* __restrict__ ws)
{
  int bid = blockIdx.x, tid = threadIdx.x;
  if (bid < 2048) {
    int gid = bid*256 + tid;
    int m = gid >> 7;       // 0..4095
    int j = gid & 127;
    int side = m >> 11;
    int n = m & 2047;
    const float* F  = side ? tf : wf;
    const float* Pw = side ? tp_w : wp_w;
    const float* Pb = side ? tp_b : wp_b;
    float4 x  = *(const float4*)&F[n*4];
    float4 wv = *(const float4*)&Pw[j*4];
    float v = x.x*wv.x + x.y*wv.y + x.z*wv.z + x.w*wv.w + Pb[j];
    ws[(side ? TH_OFF : WH_OFF) + n*H + j] = v;
  } else if (bid == 2048) {
    __shared__ float fs[2][32][4];
    {
      int side = tid >> 7, r = tid & 127;
      int bp = r >> 2, c = r & 3;
      const float* F = side ? tf : wf;
      float s = 0.f;
      #pragma unroll 8
      for (int w = 0; w < 64; ++w) s += F[bp*256 + w*4 + c];
      fs[side][bp][c] = s;
    }
    __syncthreads();
    {
      int side = tid >> 7, j = tid & 127;
      const float* Pw = side ? tp_w : wp_w;
      const float* Pb = side ? tp_b : wp_b;
      float4 wv = *(const float4*)&Pw[j*4];
      float pb = Pb[j] * 64.f;
      float* dst = ws + (side ? THS_OFF : WHS_OFF) + j;
      #pragma unroll 4
      for (int bp = 0; bp < 32; ++bp) {
        float4 f = *(const float4*)&fs[side][bp][0];
        dst[bp*128] = f.x*wv.x + f.y*wv.y + f.z*wv.z + f.w*wv.w + pb;
      }
    }
    if (tid < 128) {
      int j = tid;
      float s1 = 0.f, s0 = 0.f;
      for (int k = 0; k < 128; ++k) {
        float ec = eu_w[j*384 + 256 + k];
        s1 = fmaf(ec, ep_w[k], s1);
        s0 = fmaf(ec, ep_b[k], s0);
      }
      ws[V1_OFF + j] = s1;
      ws[C0_OFF + j] = s0 + eu_b[j];
    }
  } else {
    __shared__ float T[128*133];
    int tt = bid - 2049;
    const float* src; int rs = 384, co = 0, row0 = 0, dsto, ldd, j0;
    switch (tt) {
      case 0:  src=eu_w;  dsto=WT1_OFF; ldd=640; j0=0;   break;
      case 1:  src=wm_w;  dsto=WT1_OFF; ldd=640; j0=128; break;
      case 2: case 3: case 4:
        src=whh_w; rs=128; row0=(tt-2)*128; dsto=WT1_OFF; ldd=640; j0=256+(tt-2)*128; break;
      case 5:  src=eu_w;  co=128; dsto=WT2_OFF; ldd=640; j0=0; break;
      case 6:  src=tm_w;  dsto=WT2_OFF; ldd=640; j0=128; break;
      case 7: case 8: case 9:
        src=whh_t; rs=128; row0=(tt-7)*128; dsto=WT2_OFF; ldd=640; j0=256+(tt-7)*128; break;
      case 10: src=wm_w; co=256; dsto=WCT_OFF; ldd=128; j0=0; break;
      case 11: src=tm_w; co=256; dsto=TCT_OFF; ldd=128; j0=0; break;
      case 12: src=wm_w; co=128; dsto=WBT_OFF; ldd=128; j0=0; break;
      case 13: src=tm_w; co=128; dsto=TBT_OFF; ldd=128; j0=0; break;
      case 14: case 15: case 16:
        src=wih_w; rs=128; row0=(tt-14)*128; dsto=WIHWT_OFF; ldd=384; j0=(tt-14)*128; break;
      default:
        src=wih_t; rs=128; row0=(tt-17)*128; dsto=WIHTT_OFF; ldd=384; j0=(tt-17)*128; break;
    }
    #pragma unroll
    for (int q = 0; q < 16; ++q) {
      int idx = q*1024 + tid*4;
      int r = idx >> 7, c = idx & 127;
      float4 v = *(const float4*)&src[(row0 + r)*rs + co + c];
      float* t = &T[r*133 + c];
      t[0]=v.x; t[1]=v.y; t[2]=v.z; t[3]=v.w;
    }
    __syncthreads();
    float* dst = ws + dsto;
    #pragma unroll
    for (int q = 0; q < 64; ++q) {
      int idx = q*256 + tid;
      int k = idx >> 7, j = idx & 127;
      dst[k*ldd + j0 + j] = T[j*133 + k];
    }
  }
}

// ---------------- GEMM cores ----------------
#define FMA4(A, s, Wv) do { A.x = fmaf(s, Wv.x, A.x); A.y = fmaf(s, Wv.y, A.y); \
                            A.z = fmaf(s, Wv.z, A.z); A.w = fmaf(s, Wv.w, A.w); } while (0)

DEV void stage_x32(float* Xs, const float* __restrict__ X, int row0, int tid) {
  const float* src = X + row0*128;
  #pragma unroll
  for (int q = 0; q < 4; ++q) {
    int idx = q*1024 + tid*4;
    *(float4*)&Xs[idx] = *(const float4*)&src[idx];
  }
}

DEV void stage_x64(float* Xs, const float* __restrict__ X, int row0, int tid) {
  const float* src = X + row0*128;
  #pragma unroll
  for (int q = 0; q < 8; ++q) {
    int idx = q*1024 + tid*4;
    *(float4*)&Xs[idx] = *(const float4*)&src[idx];
  }
}

DEV void stage_x_sum8(float* Xs, const float* __restrict__ base, int row0, int tid) {
  #pragma unroll
  for (int q = 0; q < 4; ++q) {
    int idx = q*1024 + tid*4;
    float4 s = *(const float4*)&base[row0*128 + idx];
    #pragma unroll
    for (int wt = 1; wt < 8; ++wt) {
      float4 v = *(const float4*)&base[wt*(NR*H) + row0*128 + idx];
      s.x += v.x; s.y += v.y; s.z += v.z; s.w += v.w;
    }
    *(float4*)&Xs[idx] = s;
  }
}

DEV void gemm_core32(const float* __restrict__ Wt, int ldw, int j0,
                     const float* Xs, float* Ws, int tid, float4 acc[4])
{
  const int tc = tid & 31, tr = tid >> 5;
  const int jj = tc*4, r0 = tr*4;
  #pragma unroll
  for (int i = 0; i < 4; ++i) acc[i] = make_float4(0.f, 0.f, 0.f, 0.f);
  for (int kc = 0; kc < 128; kc += 32) {
    __syncthreads();
    #pragma unroll
    for (int q = 0; q < 4; ++q) {
      int idx = q*1024 + tid*4;
      int kk = idx >> 7, j = idx & 127;
      *(float4*)&Ws[idx] = *(const float4*)&Wt[(kc+kk)*ldw + j0 + j];
    }
    __syncthreads();
    #pragma unroll
    for (int kk = 0; kk < 32; kk += 4) {
      float4 w0 = *(const float4*)&Ws[(kk+0)*128 + jj];
      float4 w1 = *(const float4*)&Ws[(kk+1)*128 + jj];
      float4 w2 = *(const float4*)&Ws[(kk+2)*128 + jj];
      float4 w3 = *(const float4*)&Ws[(kk+3)*128 + jj];
      #pragma unroll
      for (int rr = 0; rr < 4; ++rr) {
        float4 xq = *(const float4*)&Xs[(r0+rr)*128 + kc + kk];
        FMA4(acc[rr], xq.x, w0);
        FMA4(acc[rr], xq.y, w1);
        FMA4(acc[rr], xq.z, w2);
        FMA4(acc[rr], xq.w, w3);
      }
    }
  }
}

DEV void gemm_core64(const float* __restrict__ Wt, int ldw, int j0,
                     const float* Xs, float* Ws, int tid, float4 acc[8])
{
  const int tc = tid & 31, tr = tid >> 5;
  const int jj = tc*4, r0 = tr*8;
  #pragma unroll
  for (int i = 0; i < 8; ++i) acc[i] = make_float4(0.f, 0.f, 0.f, 0.f);
  for (int kc = 0; kc < 128; kc += 32) {
    __syncthreads();
    #pragma unroll
    for (int q = 0; q < 4; ++q) {
      int idx = q*1024 + tid*4;
      int kk = idx >> 7, j = idx & 127;
      *(float4*)&Ws[idx] = *(const float4*)&Wt[(kc+kk)*ldw + j0 + j];
    }
    __syncthreads();
    #pragma unroll
    for (int kk = 0; kk < 32; kk += 4) {
      float4 w0 = *(const float4*)&Ws[(kk+0)*128 + jj];
      float4 w1 = *(const float4*)&Ws[(kk+1)*128 + jj];
      float4 w2 = *(const float4*)&Ws[(kk+2)*128 + jj];
      float4 w3 = *(const float4*)&Ws[(kk+3)*128 + jj];
      #pragma unroll
      for (int rr = 0; rr < 8; ++rr) {
        float4 xq = *(const float4*)&Xs[(r0+rr)*128 + kc + kk];
        FMA4(acc[rr], xq.x, w0);
        FMA4(acc[rr], xq.y, w1);
        FMA4(acc[rr], xq.z, w2);
        FMA4(acc[rr], xq.w, w3);
      }
    }
  }
}

// ---------------- KB: OUT1/OUT2 = {wh,th} @ WT^T (64-row tiles) + WBV/TBV -----------
__global__ __launch_bounds__(256) void kb_gemm1(float* __restrict__ ws)
{
  __shared__ float Xs[64*128];
  __shared__ float Wsh[32*128];
  int bid = blockIdx.x, tid = threadIdx.x;
  const int tc = tid & 31, tr = tid >> 5;
  const int jj = tc*4;
  if (bid < 320) {
    int side = bid >= 160;
    int b2 = bid - (side ? 160 : 0);
    int rt = b2 & 31, ct = b2 >> 5;      // 32 row tiles x 5 col tiles
    int row0 = rt*64;
    stage_x64(Xs, ws + (side ? TH_OFF : WH_OFF), row0, tid);
    float4 acc[8];
    gemm_core64(ws + (side ? WT2_OFF : WT1_OFF), 640, ct*128, Xs, Wsh, tid, acc);
    float* C = ws + (side ? OUT2_OFF : OUT1_OFF);
    const int r0 = tr*8;
    #pragma unroll
    for (int rr = 0; rr < 8; ++rr)
      *(float4*)&C[(row0+r0+rr)*640 + ct*128 + jj] = acc[rr];
  } else {
    int which = bid - 320;               // 0: WBV = THS@wb^T, 1: TBV = WHS@tb^T
    stage_x32(Xs, ws + (which ? WHS_OFF : THS_OFF), 0, tid);
    float4 acc[4];
    gemm_core32(ws + (which ? TBT_OFF : WBT_OFF), 128, 0, Xs, Wsh, tid, acc);
    float* C = ws + (which ? TBV_OFF : WBV_OFF);
    const int r0 = tr*4;
    #pragma unroll
    for (int rr = 0; rr < 4; ++rr)
      *(float4*)&C[(r0+rr)*128 + jj] = acc[rr];
  }
}

// ---------------- KC: edge tanh + both edge sums (256 blocks, 8 w's each) -----------
__global__ __launch_bounds__(256) void kc_edge(
    const float* __restrict__ ef, float* __restrict__ ws, float* __restrict__ out)
{
  __shared__ float Bs[64*128];     // Bt slice for this bp
  __shared__ float e_lds[8*64];
  __shared__ float red[2][8][128];
  int bid = blockIdx.x, tid = threadIdx.x;
  int bp = bid >> 3, wq = bid & 7;        // 8 w's per block
  int j = tid & 127, tsel = tid >> 7;
  float v1j = ws[V1_OFF + j], c0j = ws[C0_OFF + j];
  {
    const float* o2 = ws + OUT2_OFF + bp*64*640;
    #pragma unroll
    for (int q = 0; q < 8; ++q) {
      int idx = q*256 + tid;
      int t = idx >> 5, jq = (idx & 31)*4;
      *(float4*)&Bs[t*128 + jq] = *(const float4*)&o2[t*640 + jq];
    }
  }
  if (tid < 128) {
    int w = tid >> 4, t4 = (tid & 15)*4;
    *(float4*)&e_lds[w*64 + t4] = *(const float4*)&ef[bp*4096 + (wq*8 + w)*64 + t4];
  }
  float a_reg[8];
  #pragma unroll
  for (int w = 0; w < 8; ++w)
    a_reg[w] = ws[OUT1_OFF + (bp*64 + wq*8 + w)*640 + j];
  __syncthreads();
  float tsum[8] = {0,0,0,0,0,0,0,0};
  float* edst = out + 524288 + (bp*64 + wq*8)*8192 + j;   // + w*8192 + t*128
  float* pdst = ws + ESTP_OFF + wq*(NR*H) + bp*64*128 + j;
  for (int i = 0; i < 32; ++i) {
    int t = 2*i + tsel;
    float base = Bs[t*128 + j] + c0j;
    float wsum = 0.f;
    #pragma unroll
    for (int w = 0; w < 8; ++w) {
      float ev = e_lds[w*64 + t];
      float pre = a_reg[w] + fmaf(ev, v1j, base);
      float hv = fast_tanh(pre);
      __builtin_nontemporal_store(hv, &edst[w*8192 + t*128]);
      tsum[w] += hv;
      wsum += hv;
    }
    pdst[t*128] = wsum;
  }
  #pragma unroll
  for (int w = 0; w < 8; ++w) red[tsel][w][j] = tsum[w];
  __syncthreads();
  if (tsel == 0) {
    #pragma unroll
    for (int w = 0; w < 8; ++w)
      ws[ESW_OFF + (bp*64 + wq*8 + w)*128 + j] = red[0][w][j] + red[1][w][j];
  }
}

// ---------------- KD: msgs = edge_sum @ wc^T + T*WA + WBv + T*bias ----------------
__global__ __launch_bounds__(256) void kd_gemm2(
    float* __restrict__ ws, const float* __restrict__ wm_b, const float* __restrict__ tm_b)
{
  __shared__ float Xs[32*128];
  __shared__ float Wsh[32*128];
  int bid = blockIdx.x, tid = threadIdx.x;
  int side = bid >> 6, rt = bid & 63;
  int row0 = rt*32;
  const int tc = tid & 31, tr = tid >> 5;
  const int jj = tc*4, r0 = tr*4;
  if (side == 0) stage_x32(Xs, ws + ESW_OFF, row0, tid);
  else           stage_x_sum8(Xs, ws + ESTP_OFF, row0, tid);
  float4 acc[4];
  gemm_core32(ws + (side ? TCT_OFF : WCT_OFF), 128, 0, Xs, Wsh, tid, acc);
  const float* OUTx = ws + (side ? OUT2_OFF : OUT1_OFF);
  const float* BV   = ws + (side ? TBV_OFF : WBV_OFF);
  const float* mb   = side ? tm_b : wm_b;
  float* MSG        = ws + (side ? MSGT_OFF : MSGW_OFF);
  float4 b4 = *(const float4*)&mb[jj];
  #pragma unroll
  for (int rr = 0; rr < 4; ++rr) {
    int n = row0 + r0 + rr;
    float4 wa4 = *(const float4*)&OUTx[n*640 + 128 + jj];
    float4 bv4 = *(const float4*)&BV[(n >> 6)*128 + jj];
    float4 r;
    r.x = acc[rr].x + 64.f*(wa4.x + b4.x) + bv4.x;
    r.y = acc[rr].y + 64.f*(wa4.y + b4.y) + bv4.y;
    r.z = acc[rr].z + 64.f*(wa4.z + b4.z) + bv4.z;
    r.w = acc[rr].w + 64.f*(wa4.w + b4.w) + bv4.w;
    *(float4*)&MSG[n*128 + jj] = r;
  }
}

// ---------------- KE: gi = msgs @ w_ih^T ----------------
__global__ __launch_bounds__(256) void ke_gemm3(float* __restrict__ ws)
{
  __shared__ float Xs[32*128];
  __shared__ float Wsh[32*128];
  int bid = blockIdx.x, tid = threadIdx.x;
  int side = bid >= 192;
  int b2 = bid - (side ? 192 : 0);
  int rt = b2 & 63, ct = b2 >> 6;       // 64 row tiles x 3 col tiles
  int row0 = rt*32;
  const int tc = tid & 31, tr = tid >> 5;
  const int jj = tc*4, r0 = tr*4;
  stage_x32(Xs, ws + (side ? MSGT_OFF : MSGW_OFF), row0, tid);
  float4 acc[4];
  gemm_core32(ws + (side ? WIHTT_OFF : WIHWT_OFF), 384, ct*128, Xs, Wsh, tid, acc);
  float* C = ws + (side ? GIT_OFF : GIW_OFF);
  #pragma unroll
  for (int rr = 0; rr < 4; ++rr)
    *(float4*)&C[(row0+r0+rr)*384 + ct*128 + jj] = acc[rr];
}

// ---------------- KF: GRU gates (vectorized float4) ----------------
__global__ __launch_bounds__(256) void kf_gru(
    const float* __restrict__ ws, float* __restrict__ out,
    const float* __restrict__ bih_w, const float* __restrict__ bhh_w,
    const float* __restrict__ bih_t, const float* __restrict__ bhh_t)
{
  int gid = blockIdx.x*256 + threadIdx.x;   // 131072 threads, 4 j's each
  int jj = (gid & 31)*4;
  int n  = (gid >> 5) & 2047;
  int side = gid >> 16;
  const float* GI = ws + (side ? GIT_OFF : GIW_OFF) + n*384;
  const float* GH = ws + (side ? OUT2_OFF : OUT1_OFF) + n*640 + 256;
  const float* Hv = ws + (side ? TH_OFF : WH_OFF) + n*128;
  const float* bi = side ? bih_t : bih_w;
  const float* bh = side ? bhh_t : bhh_w;
  float4 gir = *(const float4*)&GI[jj];
  float4 giz = *(const float4*)&GI[128 + jj];
  float4 gin = *(const float4*)&GI[256 + jj];
  float4 ghr = *(const float4*)&GH[jj];
  float4 ghz = *(const float4*)&GH[128 + jj];
  float4 ghn = *(const float4*)&GH[256 + jj];
  float4 bir = *(const float4*)&bi[jj];
  float4 biz = *(const float4*)&bi[128 + jj];
  float4 bin = *(const float4*)&bi[256 + jj];
  float4 bhr = *(const float4*)&bh[jj];
  float4 bhz = *(const float4*)&bh[128 + jj];
  float4 bhn = *(const float4*)&bh[256 + jj];
  float4 h4  = *(const float4*)&Hv[jj];
  float4 o;
  #define GRU1(c) do { \
    float r = fast_sigmoid(gir.c + bir.c + ghr.c + bhr.c); \
    float z = fast_sigmoid(giz.c + biz.c + ghz.c + bhz.c); \
    float nn = fast_tanh(gin.c + bin.c + r*(ghn.c + bhn.c)); \
    o.c = (1.f - z)*nn + z*h4.c; } while (0)
  GRU1(x); GRU1(y); GRU1(z); GRU1(w);
  #undef GRU1
  __builtin_nontemporal_store(o.x, &out[side*262144 + n*128 + jj + 0]);
  __builtin_nontemporal_store(o.y, &out[side*262144 + n*128 + jj + 1]);
  __builtin_nontemporal_store(o.z, &out[side*262144 + n*128 + jj + 2]);
  __builtin_nontemporal_store(o.w, &out[side*262144 + n*128 + jj + 3]);
}

extern "C" void kernel_launch(void* const* d_in, const int* in_sizes, int n_in,
                              void* d_out, int out_size, void* d_ws, size_t ws_size,
                              hipStream_t stream)
{
  const float* wf    = (const float*)d_in[0];
  const float* tf    = (const float*)d_in[1];
  const float* ef    = (const float*)d_in[2];
  const float* wp_w  = (const float*)d_in[3];
  const float* wp_b  = (const float*)d_in[4];
  const float* tp_w  = (const float*)d_in[5];
  const float* tp_b  = (const float*)d_in[6];
  const float* ep_w  = (const float*)d_in[7];
  const float* ep_b  = (const float*)d_in[8];
  const float* eu_w  = (const float*)d_in[9];
  const float* eu_b  = (const float*)d_in[10];
  const float* wm_w  = (const float*)d_in[11];
  const float* wm_b  = (const float*)d_in[12];
  const float* tm_w  = (const float*)d_in[13];
  const float* tm_b  = (const float*)d_in[14];
  const float* wih_w = (const float*)d_in[15];
  const float* whh_w = (const float*)d_in[16];
  const float* bih_w = (const float*)d_in[17];
  const float* bhh_w = (const float*)d_in[18];
  const float* wih_t = (const float*)d_in[19];
  const float* whh_t = (const float*)d_in[20];
  const float* bih_t = (const float*)d_in[21];
  const float* bhh_t = (const float*)d_in[22];
  float* ws  = (float*)d_ws;
  float* out = (float*)d_out;

  hipLaunchKernelGGL(ka_prep, dim3(2069), dim3(256), 0, stream,
                     wf, tf, wp_w, wp_b, tp_w, tp_b, eu_w, wm_w, tm_w,
                     whh_w, whh_t, wih_w, wih_t, ep_w, ep_b, eu_b, ws);
  hipLaunchKernelGGL(kb_gemm1, dim3(322),  dim3(256), 0, stream, ws);
  hipLaunchKernelGGL(kc_edge,  dim3(256),  dim3(256), 0, stream, ef, ws, out);
  hipLaunchKernelGGL(kd_gemm2, dim3(128),  dim3(256), 0, stream, ws, wm_b, tm_b);
  hipLaunchKernelGGL(ke_gemm3, dim3(384),  dim3(256), 0, stream, ws);
  hipLaunchKernelGGL(kf_gru,   dim3(512),  dim3(256), 0, stream, ws, out,
                     bih_w, bhh_w, bih_t, bhh_t);
}

// Round 7
// 176.929 us; speedup vs baseline: 1.6684x; 1.0545x over previous
//
#include <hip/hip_runtime.h>

#define DEV __device__ __forceinline__

constexpr int H  = 128;
constexpr int BP = 32;        // B*P
constexpr int NR = 2048;      // BP*64 rows

// workspace layout (float offsets)
constexpr int WH_OFF    = 0;                       // [2048][128] weapon_h
constexpr int TH_OFF    = WH_OFF + NR*H;           // [2048][128] target_h
constexpr int V1_OFF    = TH_OFF + NR*H;           // [128]
constexpr int C0_OFF    = V1_OFF + H;              // [128]
constexpr int WT1_OFF   = C0_OFF + H;              // [128][640]  eaT|waT|whh_wT
constexpr int WT2_OFF   = WT1_OFF + 128*640;       // [128][640]  ebT|taT|whh_tT
constexpr int WCT_OFF   = WT2_OFF + 128*640;       // [128][128]
constexpr int TCT_OFF   = WCT_OFF + 128*128;
constexpr int WIHWT_OFF = TCT_OFF + 128*128;       // [128][384]
constexpr int WIHTT_OFF = WIHWT_OFF + 128*384;
constexpr int WBT_OFF   = WIHTT_OFF + 128*384;     // [128][128]
constexpr int TBT_OFF   = WBT_OFF + 128*128;
constexpr int OUT1_OFF  = TBT_OFF + 128*128;       // [2048][640]  A|WA|ghw
constexpr int OUT2_OFF  = OUT1_OFF + NR*640;       // [2048][640]  Bt|TA|ght
constexpr int ESW_OFF   = OUT2_OFF + NR*640;       // [2048][128] edge sum over t
constexpr int ESTP_OFF  = ESW_OFF + NR*H;          // [8][2048][128] partial sums over w
constexpr int WBV_OFF   = ESTP_OFF + 8*NR*H;       // [32][128]
constexpr int TBV_OFF   = WBV_OFF + BP*H;          // [32][128]

DEV float fast_tanh(float x) {
  float e = __builtin_amdgcn_exp2f(x * 2.8853900817779268f);  // exp(2x)
  return fmaf(-2.0f, __builtin_amdgcn_rcpf(e + 1.0f), 1.0f);
}
DEV float fast_sigmoid(float x) {
  float e = __builtin_amdgcn_exp2f(x * -1.4426950408889634f); // exp(-x)
  return __builtin_amdgcn_rcpf(1.0f + e);
}

// ---------------- K0: weight transposes (LDS-tiled) + v1/c0 ----------------
__global__ __launch_bounds__(256) void k0_prep(
    const float* __restrict__ eu_w, const float* __restrict__ wm_w,
    const float* __restrict__ tm_w,
    const float* __restrict__ whh_w, const float* __restrict__ whh_t,
    const float* __restrict__ wih_w, const float* __restrict__ wih_t,
    const float* __restrict__ ep_w, const float* __restrict__ ep_b,
    const float* __restrict__ eu_b,
    float* __restrict__ ws)
{
  __shared__ float T[128*133];
  __shared__ float epl[128], ebl[128];
  int tt = blockIdx.x, tid = threadIdx.x;
  const float* src; int rs = 384, co = 0, row0 = 0, dsto = 0, ldd = 0, j0 = 0;
  switch (tt) {
    case 0:  src=eu_w;  dsto=WT1_OFF; ldd=640; j0=0;   break;
    case 1:  src=wm_w;  dsto=WT1_OFF; ldd=640; j0=128; break;
    case 2: case 3: case 4:
      src=whh_w; rs=128; row0=(tt-2)*128; dsto=WT1_OFF; ldd=640; j0=256+(tt-2)*128; break;
    case 5:  src=eu_w;  co=128; dsto=WT2_OFF; ldd=640; j0=0; break;
    case 6:  src=tm_w;  dsto=WT2_OFF; ldd=640; j0=128; break;
    case 7: case 8: case 9:
      src=whh_t; rs=128; row0=(tt-7)*128; dsto=WT2_OFF; ldd=640; j0=256+(tt-7)*128; break;
    case 10: src=wm_w; co=256; dsto=WCT_OFF; ldd=128; j0=0; break;
    case 11: src=tm_w; co=256; dsto=TCT_OFF; ldd=128; j0=0; break;
    case 12: src=wm_w; co=128; dsto=WBT_OFF; ldd=128; j0=0; break;
    case 13: src=tm_w; co=128; dsto=TBT_OFF; ldd=128; j0=0; break;
    case 14: case 15: case 16:
      src=wih_w; rs=128; row0=(tt-14)*128; dsto=WIHWT_OFF; ldd=384; j0=(tt-14)*128; break;
    case 17: case 18: case 19:
      src=wih_t; rs=128; row0=(tt-17)*128; dsto=WIHTT_OFF; ldd=384; j0=(tt-17)*128; break;
    default: src=eu_w; co=256; break;   // tt==20: ec slice for v1/c0
  }
  #pragma unroll
  for (int q = 0; q < 16; ++q) {
    int idx = q*1024 + tid*4;
    int r = idx >> 7, c = idx & 127;
    float4 v = *(const float4*)&src[(row0 + r)*rs + co + c];
    float* t = &T[r*133 + c];
    t[0]=v.x; t[1]=v.y; t[2]=v.z; t[3]=v.w;
  }
  if (tt == 20 && tid >= 128) {
    epl[tid-128] = ep_w[tid-128];
    ebl[tid-128] = ep_b[tid-128];
  }
  __syncthreads();
  if (tt == 20) {
    if (tid < 128) {
      float s1 = 0.f, s0 = 0.f;
      #pragma unroll 8
      for (int k = 0; k < 128; ++k) {
        float ec = T[tid*133 + k];
        s1 = fmaf(ec, epl[k], s1);
        s0 = fmaf(ec, ebl[k], s0);
      }
      ws[V1_OFF + tid] = s1;
      ws[C0_OFF + tid] = s0 + eu_b[tid];
    }
    return;
  }
  float* dst = ws + dsto;
  #pragma unroll
  for (int q = 0; q < 64; ++q) {
    int idx = q*256 + tid;
    int k = idx >> 7, j = idx & 127;
    dst[k*ldd + j0 + j] = T[j*133 + k];
  }
}

// ---------------- GEMM core (templated row-repeat) ----------------
#define FMA4(A, s, Wv) do { A.x = fmaf(s, Wv.x, A.x); A.y = fmaf(s, Wv.y, A.y); \
                            A.z = fmaf(s, Wv.z, A.z); A.w = fmaf(s, Wv.w, A.w); } while (0)

template<int RPT>
DEV void gemm_coreN(const float* __restrict__ Wt, int ldw, int j0,
                    const float* Xs, float* Ws, int tid, float4* acc)
{
  const int tc = tid & 31, tr = tid >> 5;
  const int jj = tc*4, r0 = tr*RPT;
  #pragma unroll
  for (int i = 0; i < RPT; ++i) acc[i] = make_float4(0.f, 0.f, 0.f, 0.f);
  for (int kc = 0; kc < 128; kc += 32) {
    __syncthreads();
    #pragma unroll
    for (int q = 0; q < 4; ++q) {
      int idx = q*1024 + tid*4;
      int kk = idx >> 7, j = idx & 127;
      *(float4*)&Ws[idx] = *(const float4*)&Wt[(kc+kk)*ldw + j0 + j];
    }
    __syncthreads();
    #pragma unroll
    for (int kk = 0; kk < 32; kk += 4) {
      float4 w0 = *(const float4*)&Ws[(kk+0)*128 + jj];
      float4 w1 = *(const float4*)&Ws[(kk+1)*128 + jj];
      float4 w2 = *(const float4*)&Ws[(kk+2)*128 + jj];
      float4 w3 = *(const float4*)&Ws[(kk+3)*128 + jj];
      #pragma unroll
      for (int rr = 0; rr < RPT; ++rr) {
        float4 xq = *(const float4*)&Xs[(r0+rr)*128 + kc + kk];
        FMA4(acc[rr], xq.x, w0);
        FMA4(acc[rr], xq.y, w1);
        FMA4(acc[rr], xq.z, w2);
        FMA4(acc[rr], xq.w, w3);
      }
    }
  }
}

// ---------------- K1: gemm1 with on-the-fly X projection + BV blocks ----------------
__global__ __launch_bounds__(256) void k1_gemm1(
    const float* __restrict__ wf, const float* __restrict__ tf,
    const float* __restrict__ wp_w, const float* __restrict__ wp_b,
    const float* __restrict__ tp_w, const float* __restrict__ tp_b,
    float* __restrict__ ws)
{
  __shared__ float Xs[64*128];
  __shared__ float Wsh[32*128];
  __shared__ float4 Fls[64];
  __shared__ float4 Wls[128];
  __shared__ float  Bls[128];
  __shared__ float  fs[32][4];
  int bid = blockIdx.x, tid = threadIdx.x;
  const int tc = tid & 31, tr = tid >> 5;
  const int jj = tc*4;
  if (bid < 320) {
    int side = bid >= 160;
    int b2 = bid - (side ? 160 : 0);
    int rt = b2 & 31, ct = b2 >> 5;      // 32 row tiles x 5 col tiles
    int row0 = rt*64;
    const float* F  = side ? tf : wf;
    const float* Pw = side ? tp_w : wp_w;
    const float* Pb = side ? tp_b : wp_b;
    if (tid < 64)        Fls[tid]     = *(const float4*)&F[(row0 + tid)*4];
    else if (tid < 192)  Wls[tid-64]  = *(const float4*)&Pw[(tid-64)*4];
    else { int j = (tid-192)*2; Bls[j] = Pb[j]; Bls[j+1] = Pb[j+1]; }
    __syncthreads();
    {
      int j = tid & 127, half = tid >> 7;
      float4 wv = Wls[j]; float b = Bls[j];
      #pragma unroll
      for (int rr = 0; rr < 32; ++rr) {
        int r = half*32 + rr;
        float4 f = Fls[r];
        Xs[r*128 + j] = f.x*wv.x + f.y*wv.y + f.z*wv.z + f.w*wv.w + b;
      }
    }
    float4 acc[8];
    gemm_coreN<8>(ws + (side ? WT2_OFF : WT1_OFF), 640, ct*128, Xs, Wsh, tid, acc);
    float* C = ws + (side ? OUT2_OFF : OUT1_OFF);
    const int r0 = tr*8;
    #pragma unroll
    for (int rr = 0; rr < 8; ++rr)
      *(float4*)&C[(row0+r0+rr)*640 + ct*128 + jj] = acc[rr];
    if (ct == 0) {   // persist wh/th rows for K3's h (Xs stable; barriers inside gemm passed)
      float* Hdst = ws + (side ? TH_OFF : WH_OFF) + row0*128;
      #pragma unroll
      for (int q = 0; q < 8; ++q) {
        int idx = q*1024 + tid*4;
        *(float4*)&Hdst[idx] = *(const float4*)&Xs[idx];
      }
    }
  } else {
    // which==0: WBV = THS(from tf) @ wb^T ; which==1: TBV = WHS(from wf) @ tb^T
    int which = bid - 320;
    const float* F  = which ? wf : tf;
    const float* Pw = which ? wp_w : tp_w;
    const float* Pb = which ? wp_b : tp_b;
    if (tid < 128) {
      int bp = tid >> 2, c = tid & 3;
      float s = 0.f;
      #pragma unroll 8
      for (int w = 0; w < 64; ++w) s += F[bp*256 + w*4 + c];
      fs[bp][c] = s;
    } else {
      int j = tid - 128;
      Wls[j] = *(const float4*)&Pw[j*4];
      Bls[j] = Pb[j];
    }
    __syncthreads();
    {
      int j = tid & 127, half = tid >> 7;
      float4 wv = Wls[j]; float b = Bls[j]*64.f;
      #pragma unroll
      for (int rr = 0; rr < 16; ++rr) {
        int r = half*16 + rr;
        float4 f = *(const float4*)&fs[r][0];
        Xs[r*128 + j] = f.x*wv.x + f.y*wv.y + f.z*wv.z + f.w*wv.w + b;
      }
    }
    float4 acc[4];
    gemm_coreN<4>(ws + (which ? TBT_OFF : WBT_OFF), 128, 0, Xs, Wsh, tid, acc);
    float* C = ws + (which ? TBV_OFF : WBV_OFF);
    const int r0 = tr*4;
    #pragma unroll
    for (int rr = 0; rr < 4; ++rr)
      *(float4*)&C[(r0+rr)*128 + jj] = acc[rr];
  }
}

// ---------------- K2: edge tanh + both edge sums (256 blocks, 8 w's each) -----------
__global__ __launch_bounds__(256) void k2_edge(
    const float* __restrict__ ef, float* __restrict__ ws, float* __restrict__ out)
{
  __shared__ float Bs[64*128];     // Bt slice for this bp
  __shared__ float e_lds[8*64];
  __shared__ float red[2][8][128];
  int bid = blockIdx.x, tid = threadIdx.x;
  int bp = bid >> 3, wq = bid & 7;        // 8 w's per block
  int j = tid & 127, tsel = tid >> 7;
  float v1j = ws[V1_OFF + j], c0j = ws[C0_OFF + j];
  {
    const float* o2 = ws + OUT2_OFF + bp*64*640;
    #pragma unroll
    for (int q = 0; q < 8; ++q) {
      int idx = q*256 + tid;
      int t = idx >> 5, jq = (idx & 31)*4;
      *(float4*)&Bs[t*128 + jq] = *(const float4*)&o2[t*640 + jq];
    }
  }
  if (tid < 128) {
    int w = tid >> 4, t4 = (tid & 15)*4;
    *(float4*)&e_lds[w*64 + t4] = *(const float4*)&ef[bp*4096 + (wq*8 + w)*64 + t4];
  }
  float a_reg[8];
  #pragma unroll
  for (int w = 0; w < 8; ++w)
    a_reg[w] = ws[OUT1_OFF + (bp*64 + wq*8 + w)*640 + j];
  __syncthreads();
  float tsum[8] = {0,0,0,0,0,0,0,0};
  float* edst = out + 524288 + (bp*64 + wq*8)*8192 + j;   // + w*8192 + t*128
  float* pdst = ws + ESTP_OFF + wq*(NR*H) + bp*64*128 + j;
  for (int i = 0; i < 32; ++i) {
    int t = 2*i + tsel;
    float base = Bs[t*128 + j] + c0j;
    float wsum = 0.f;
    #pragma unroll
    for (int w = 0; w < 8; ++w) {
      float ev = e_lds[w*64 + t];
      float pre = a_reg[w] + fmaf(ev, v1j, base);
      float hv = fast_tanh(pre);
      __builtin_nontemporal_store(hv, &edst[w*8192 + t*128]);
      tsum[w] += hv;
      wsum += hv;
    }
    pdst[t*128] = wsum;
  }
  #pragma unroll
  for (int w = 0; w < 8; ++w) red[tsel][w][j] = tsum[w];
  __syncthreads();
  if (tsel == 0) {
    #pragma unroll
    for (int w = 0; w < 8; ++w)
      ws[ESW_OFF + (bp*64 + wq*8 + w)*128 + j] = red[0][w][j] + red[1][w][j];
  }
}

// ---------------- K3: fused msgs -> gi -> GRU gates (16-row tiles) ----------------
__global__ __launch_bounds__(256) void k3_fused(
    float* __restrict__ ws, float* __restrict__ out,
    const float* __restrict__ wm_b, const float* __restrict__ tm_b,
    const float* __restrict__ bih_w, const float* __restrict__ bhh_w,
    const float* __restrict__ bih_t, const float* __restrict__ bhh_t)
{
  __shared__ float Xin[16*128];
  __shared__ float Xm[16*128];
  __shared__ float Wsh[32*128];
  int bid = blockIdx.x, tid = threadIdx.x;
  int side = bid >> 7, rt = bid & 127, row0 = rt*16;
  const int tc = tid & 31, tr = tid >> 5;
  const int jj = tc*4;
  // stage Xin (ESW rows for side 0; sum of 8 ESTP slabs for side 1)
  #pragma unroll
  for (int q = 0; q < 2; ++q) {
    int idx = q*1024 + tid*4;
    float4 v;
    if (side == 0) {
      v = *(const float4*)&ws[ESW_OFF + row0*128 + idx];
    } else {
      v = *(const float4*)&ws[ESTP_OFF + row0*128 + idx];
      #pragma unroll
      for (int wt = 1; wt < 8; ++wt) {
        float4 u = *(const float4*)&ws[ESTP_OFF + wt*(NR*H) + row0*128 + idx];
        v.x += u.x; v.y += u.y; v.z += u.z; v.w += u.w;
      }
    }
    *(float4*)&Xin[idx] = v;
  }
  // msgs = Xin @ wc^T + 64*WA + BV + 64*b   -> Xm
  float4 accm[2];
  gemm_coreN<2>(ws + (side ? TCT_OFF : WCT_OFF), 128, 0, Xin, Wsh, tid, accm);
  const float* OUTx = ws + (side ? OUT2_OFF : OUT1_OFF);
  {
    const float* BV = ws + (side ? TBV_OFF : WBV_OFF);
    const float* mb = side ? tm_b : wm_b;
    float4 b4 = *(const float4*)&mb[jj];
    #pragma unroll
    for (int rr = 0; rr < 2; ++rr) {
      int r = tr*2 + rr, n = row0 + r;
      float4 wa4 = *(const float4*)&OUTx[n*640 + 128 + jj];
      float4 bv4 = *(const float4*)&BV[(n >> 6)*128 + jj];
      float4 m;
      m.x = accm[rr].x + 64.f*(wa4.x + b4.x) + bv4.x;
      m.y = accm[rr].y + 64.f*(wa4.y + b4.y) + bv4.y;
      m.z = accm[rr].z + 64.f*(wa4.z + b4.z) + bv4.z;
      m.w = accm[rr].w + 64.f*(wa4.w + b4.w) + bv4.w;
      *(float4*)&Xm[r*128 + jj] = m;
    }
  }
  // gi = Xm @ w_ih^T  (3 col tiles; first barrier of gemm_coreN covers Xm writes)
  const float* WIH = ws + (side ? WIHTT_OFF : WIHWT_OFF);
  float4 ar[2], az[2], an[2];
  gemm_coreN<2>(WIH, 384, 0,   Xm, Wsh, tid, ar);
  gemm_coreN<2>(WIH, 384, 128, Xm, Wsh, tid, az);
  gemm_coreN<2>(WIH, 384, 256, Xm, Wsh, tid, an);
  // GRU gates
  {
    const float* Hsrc = ws + (side ? TH_OFF : WH_OFF);
    const float* bi = side ? bih_t : bih_w;
    const float* bh = side ? bhh_t : bhh_w;
    float4 bir = *(const float4*)&bi[jj];
    float4 biz = *(const float4*)&bi[128 + jj];
    float4 bin = *(const float4*)&bi[256 + jj];
    float4 bhr = *(const float4*)&bh[jj];
    float4 bhz = *(const float4*)&bh[128 + jj];
    float4 bhn = *(const float4*)&bh[256 + jj];
    #pragma unroll
    for (int rr = 0; rr < 2; ++rr) {
      int n = row0 + tr*2 + rr;
      float4 ghr = *(const float4*)&OUTx[n*640 + 256 + jj];
      float4 ghz = *(const float4*)&OUTx[n*640 + 384 + jj];
      float4 ghn = *(const float4*)&OUTx[n*640 + 512 + jj];
      float4 h4  = *(const float4*)&Hsrc[n*128 + jj];
      float4 o;
      #define GRU1(c) do { \
        float r = fast_sigmoid(ar[rr].c + bir.c + ghr.c + bhr.c); \
        float z = fast_sigmoid(az[rr].c + biz.c + ghz.c + bhz.c); \
        float nn = fast_tanh(an[rr].c + bin.c + r*(ghn.c + bhn.c)); \
        o.c = (1.f - z)*nn + z*h4.c; } while (0)
      GRU1(x); GRU1(y); GRU1(z); GRU1(w);
      #undef GRU1
      float* op = &out[side*262144 + n*128 + jj];
      __builtin_nontemporal_store(o.x, op + 0);
      __builtin_nontemporal_store(o.y, op + 1);
      __builtin_nontemporal_store(o.z, op + 2);
      __builtin_nontemporal_store(o.w, op + 3);
    }
  }
}

extern "C" void kernel_launch(void* const* d_in, const int* in_sizes, int n_in,
                              void* d_out, int out_size, void* d_ws, size_t ws_size,
                              hipStream_t stream)
{
  const float* wf    = (const float*)d_in[0];
  const float* tf    = (const float*)d_in[1];
  const float* ef    = (const float*)d_in[2];
  const float* wp_w  = (const float*)d_in[3];
  const float* wp_b  = (const float*)d_in[4];
  const float* tp_w  = (const float*)d_in[5];
  const float* tp_b  = (const float*)d_in[6];
  const float* ep_w  = (const float*)d_in[7];
  const float* ep_b  = (const float*)d_in[8];
  const float* eu_w  = (const float*)d_in[9];
  const float* eu_b  = (const float*)d_in[10];
  const float* wm_w  = (const float*)d_in[11];
  const float* wm_b  = (const float*)d_in[12];
  const float* tm_w  = (const float*)d_in[13];
  const float* tm_b  = (const float*)d_in[14];
  const float* wih_w = (const float*)d_in[15];
  const float* whh_w = (const float*)d_in[16];
  const float* bih_w = (const float*)d_in[17];
  const float* bhh_w = (const float*)d_in[18];
  const float* wih_t = (const float*)d_in[19];
  const float* whh_t = (const float*)d_in[20];
  const float* bih_t = (const float*)d_in[21];
  const float* bhh_t = (const float*)d_in[22];
  float* ws  = (float*)d_ws;
  float* out = (float*)d_out;

  hipLaunchKernelGGL(k0_prep, dim3(21), dim3(256), 0, stream,
                     eu_w, wm_w, tm_w, whh_w, whh_t, wih_w, wih_t, ep_w, ep_b, eu_b, ws);
  hipLaunchKernelGGL(k1_gemm1, dim3(322), dim3(256), 0, stream,
                     wf, tf, wp_w, wp_b, tp_w, tp_b, ws);
  hipLaunchKernelGGL(k2_edge,  dim3(256), dim3(256), 0, stream, ef, ws, out);
  hipLaunchKernelGGL(k3_fused, dim3(256), dim3(256), 0, stream, ws, out,
                     wm_b, tm_b, bih_w, bhh_w, bih_t, bhh_t);
}